// Round 2
// 2797.317 us; speedup vs baseline: 1.8862x; 1.8862x over previous
//
#include <hip/hip_runtime.h>
#include <hip/hip_bf16.h>

// TreeDecoder: B=4096, MLP 16->64->256->1024->4096 (leaky), reshape (B,64,64),
// then 3x [BinaryTreeConv -> TreeLayerNorm -> LeakyReLU], out (B,512,64) fp32.
//
// Tree-convs as bf16 MFMA GEMMs (16x16x32), one block per sample, fused
// per-sample LayerNorm+leaky epilogue. Weights hi/lo-split in bf16 so the only
// new quantization vs the fp32-VALU baseline is the conv1 input rounding.
// MFMA fragment type = ext_vector(8) short per the gfx950 guide (bf16 bits in shorts).

typedef short s16x8 __attribute__((ext_vector_type(8)));
typedef float f32x4 __attribute__((ext_vector_type(4)));
typedef unsigned int u32x4 __attribute__((ext_vector_type(4)));

__device__ __forceinline__ float leaky(float v) { return v > 0.0f ? v : 0.01f * v; }

__device__ __forceinline__ unsigned short bf_bits(float f) {
    __hip_bfloat16 h = __float2bfloat16(f);
    return __builtin_bit_cast(unsigned short, h);
}
__device__ __forceinline__ unsigned short bf_bits(__hip_bfloat16 h) {
    return __builtin_bit_cast(unsigned short, h);
}
__device__ __forceinline__ void cvt_store(float* p, float v) { *p = v; }
__device__ __forceinline__ void cvt_store(__hip_bfloat16* p, float v) { *p = __float2bfloat16(v); }

// ---------------- MLP GEMM (unchanged from verified baseline) ----------------
__global__ __launch_bounds__(256) void gemm_leaky_kernel(
    const float* __restrict__ A, const float* __restrict__ W,
    const float* __restrict__ bias, float* __restrict__ Cmat,
    int M, int N, int K)
{
    __shared__ float As[16][68];
    __shared__ float Ws[16][68];
    const int tid = threadIdx.x;
    const int tx = tid & 15, ty = tid >> 4;
    const int n0 = blockIdx.x * 64, m0 = blockIdx.y * 64;
    const int row = tid >> 2, kq = tid & 3;
    float acc[4][4] = {};

    for (int k0 = 0; k0 < K; k0 += 16) {
        const float4 a = *(const float4*)&A[(size_t)(m0 + row) * K + k0 + kq * 4];
        const float4 w = *(const float4*)&W[(size_t)(n0 + row) * K + k0 + kq * 4];
        __syncthreads();
        As[kq*4+0][row] = a.x; As[kq*4+1][row] = a.y; As[kq*4+2][row] = a.z; As[kq*4+3][row] = a.w;
        Ws[kq*4+0][row] = w.x; Ws[kq*4+1][row] = w.y; Ws[kq*4+2][row] = w.z; Ws[kq*4+3][row] = w.w;
        __syncthreads();
        #pragma unroll
        for (int kk = 0; kk < 16; ++kk) {
            float avv[4], wvv[4];
            *(float4*)avv = *(const float4*)&As[kk][ty * 4];
            *(float4*)wvv = *(const float4*)&Ws[kk][tx * 4];
            #pragma unroll
            for (int i = 0; i < 4; ++i)
                #pragma unroll
                for (int j = 0; j < 4; ++j)
                    acc[i][j] = fmaf(avv[i], wvv[j], acc[i][j]);
        }
    }
    #pragma unroll
    for (int i = 0; i < 4; ++i) {
        const int m = m0 + ty * 4 + i;
        float4 r;
        r.x = leaky(acc[i][0] + bias[n0 + tx*4 + 0]);
        r.y = leaky(acc[i][1] + bias[n0 + tx*4 + 1]);
        r.z = leaky(acc[i][2] + bias[n0 + tx*4 + 2]);
        r.w = leaky(acc[i][3] + bias[n0 + tx*4 + 3]);
        *(float4*)&Cmat[(size_t)m * N + n0 + tx * 4] = r;
    }
}

// ---------------- weight fp32 -> bf16 hi/lo split ----------------
__global__ __launch_bounds__(256) void wcast_kernel(
    const float* __restrict__ in, __hip_bfloat16* __restrict__ hi,
    __hip_bfloat16* __restrict__ lo, int n)
{
    const int i = blockIdx.x * 256 + threadIdx.x;
    if (i < n) {
        const float w = in[i];
        const __hip_bfloat16 h = __float2bfloat16(w);
        hi[i] = h;
        lo[i] = __float2bfloat16(w - __bfloat162float(h));
    }
}

// ---------------- fused BinaryTreeConv + TreeLayerNorm + LeakyReLU ----------------
// One block (256 thr = 4 waves) per sample. Wave w computes o-rows [w*O/4, (w+1)*O/4),
// all 64 node columns (node 63 = zero dummy; output slot = node+1, slot 0 = LN(0)).
// Per K-step (32 k): 256 threads gather G[k][node] into a 4KB swizzled LDS tile
// (thread = one node, 8 consecutive k, one b128 write); then MFMA 16x16x32 bf16
// with hi/lo weight split. Epilogue: block-wide mean/var -> normalize -> store once.
template <int C, int O, typename Tin, typename Tout>
__global__ __launch_bounds__(256, 2) void conv_ln_kernel(
    const Tin* __restrict__ x, const int* __restrict__ idx,
    const __hip_bfloat16* __restrict__ Whi, const __hip_bfloat16* __restrict__ Wlo,
    const float* __restrict__ bias, Tout* __restrict__ outp)
{
    constexpr int K = 3 * C;
    constexpr int KSTEPS = K / 32;
    constexpr int OT = O / 64;              // 16-row o-tiles per wave
    __shared__ __align__(16) unsigned int Gw[1024];   // [64 node][32 k] bf16, slot-XOR swizzled
    __shared__ float red[12];

    const int tid  = (int)threadIdx.x;
    const int b    = (int)blockIdx.x;
    const int lane = tid & 63;
    const int wv   = tid >> 6;

    // gather role: thread fills node `lane`, k-slot `wv` (8 consecutive k)
    const int gswz = wv ^ ((lane >> 1) & 3);            // bank-conflict-light b128 swizzle
    unsigned int* gdst = &Gw[lane * 16 + gswz * 4];
    const bool real = lane < 63;
    int j0 = 0, j1 = 0, j2 = 0;
    if (real) {
        const int* ib = idx + b * 189 + lane * 3;
        j0 = ib[0]; j1 = ib[1]; j2 = ib[2];
    }
    const Tin* xb = x + (size_t)b * C * 64;

    // mfma roles (A: row=lane&15, k=(lane>>4)*8+j ; B: col=lane&15, same k map)
    const int col  = lane & 15;
    const int kg   = lane >> 4;
    const int ldsb = col * 16 + (kg ^ ((col >> 1) & 3)) * 4;   // + nt*256 ; same XOR as write side
    const int ob   = wv * (O / 4);
    const size_t wofs = (size_t)(ob + col) * K + kg * 8;
    const __hip_bfloat16* wh = Whi + wofs;
    const __hip_bfloat16* wl = Wlo + wofs;

    f32x4 acc[OT][4];
    #pragma unroll
    for (int t = 0; t < OT; ++t)
        #pragma unroll
        for (int nt = 0; nt < 4; ++nt) acc[t][nt] = (f32x4)(0.0f);

    for (int s = 0; s < KSTEPS; ++s) {
        const int kb = s * 32 + wv * 8;
        unsigned int pk0, pk1, pk2, pk3;
        {
            unsigned short gv[8];
            int c = kb / 3;
            int r = kb - 3 * c;
            #pragma unroll
            for (int i = 0; i < 8; ++i) {
                const int j = (r == 0) ? j0 : ((r == 1) ? j1 : j2);   // no dyn-indexed array (rule #20)
                gv[i] = real ? bf_bits(xb[c * 64 + j]) : (unsigned short)0;
                ++r; if (r == 3) { r = 0; ++c; }
            }
            pk0 = (unsigned int)gv[0] | ((unsigned int)gv[1] << 16);
            pk1 = (unsigned int)gv[2] | ((unsigned int)gv[3] << 16);
            pk2 = (unsigned int)gv[4] | ((unsigned int)gv[5] << 16);
            pk3 = (unsigned int)gv[6] | ((unsigned int)gv[7] << 16);
        }
        __syncthreads();                    // previous step's fragment reads done
        u32x4 pkv = {pk0, pk1, pk2, pk3};
        *(u32x4*)gdst = pkv;
        __syncthreads();                    // tile ready

        s16x8 bfr[4];
        #pragma unroll
        for (int nt = 0; nt < 4; ++nt)
            bfr[nt] = *(const s16x8*)(const void*)&Gw[nt * 256 + ldsb];

        #pragma unroll
        for (int t = 0; t < OT; ++t) {
            const s16x8 ah = *(const s16x8*)(const void*)(wh + (size_t)t * 16 * K + s * 32);
            const s16x8 al = *(const s16x8*)(const void*)(wl + (size_t)t * 16 * K + s * 32);
            #pragma unroll
            for (int nt = 0; nt < 4; ++nt)
                acc[t][nt] = __builtin_amdgcn_mfma_f32_16x16x32_bf16(ah, bfr[nt], acc[t][nt], 0, 0, 0);
            #pragma unroll
            for (int nt = 0; nt < 4; ++nt)
                acc[t][nt] = __builtin_amdgcn_mfma_f32_16x16x32_bf16(al, bfr[nt], acc[t][nt], 0, 0, 0);
        }
    }

    // bias + per-sample stats (zero slots contribute 0 to s1/s2; count = O*64 incl. them)
    float s1 = 0.0f, s2 = 0.0f;
    #pragma unroll
    for (int t = 0; t < OT; ++t) {
        #pragma unroll
        for (int r = 0; r < 4; ++r) {
            const float bo = bias[ob + t * 16 + kg * 4 + r];
            #pragma unroll
            for (int nt = 0; nt < 4; ++nt) {
                const float v = acc[t][nt][r] + bo;
                acc[t][nt][r] = v;
                if (nt < 3 || col < 15) { s1 += v; s2 += v * v; }   // node = nt*16+col < 63
            }
        }
    }
    #pragma unroll
    for (int off = 32; off > 0; off >>= 1) {
        s1 += __shfl_down(s1, off, 64);
        s2 += __shfl_down(s2, off, 64);
    }
    if (lane == 0) { red[wv * 2] = s1; red[wv * 2 + 1] = s2; }
    __syncthreads();
    if (tid == 0) {
        const float a1 = red[0] + red[2] + red[4] + red[6];
        const float a2 = red[1] + red[3] + red[5] + red[7];
        const float cnt = (float)(O * 64);
        const float mean = a1 / cnt;
        float var = (a2 - a1 * mean) / (cnt - 1.0f);   // torch unbiased std
        var = fmaxf(var, 0.0f);
        red[8] = mean;
        red[9] = 1.0f / (sqrtf(var) + 1e-5f);
    }
    __syncthreads();
    const float mean = red[8], inv = red[9];

    Tout* op = outp + (size_t)b * O * 64;
    #pragma unroll
    for (int t = 0; t < OT; ++t) {
        #pragma unroll
        for (int r = 0; r < 4; ++r) {
            const int o = ob + t * 16 + kg * 4 + r;
            #pragma unroll
            for (int nt = 0; nt < 4; ++nt) {
                const int node = nt * 16 + col;
                if (node < 63)
                    cvt_store(&op[(size_t)o * 64 + node + 1], leaky((acc[t][nt][r] - mean) * inv));
            }
        }
    }
    const float z0 = leaky((0.0f - mean) * inv);        // LN of the zero pad slot
    for (int o = tid; o < O; o += 256) cvt_store(&op[(size_t)o * 64], z0);
}

extern "C" void kernel_launch(void* const* d_in, const int* in_sizes, int n_in,
                              void* d_out, int out_size, void* d_ws, size_t ws_size,
                              hipStream_t stream)
{
    const int B = 4096;
    const float* trees = (const float*)d_in[0];
    const int*   indexes = (const int*)d_in[1];
    const float* W1 = (const float*)d_in[2];
    const float* b1 = (const float*)d_in[3];
    const float* W2 = (const float*)d_in[4];
    const float* b2 = (const float*)d_in[5];
    const float* W3 = (const float*)d_in[6];
    const float* b3 = (const float*)d_in[7];
    const float* W4 = (const float*)d_in[8];
    const float* b4 = (const float*)d_in[9];
    const float* cw1 = (const float*)d_in[10];
    const float* cb1 = (const float*)d_in[11];
    const float* cw2 = (const float*)d_in[12];
    const float* cb2 = (const float*)d_in[13];
    const float* cw3 = (const float*)d_in[14];
    const float* cb3 = (const float*)d_in[15];
    float* out = (float*)d_out;
    char* ws = (char*)d_ws;

    // workspace layout (bytes) — same footprint as baseline (~277 MB)
    float*          x4 = (float*)(ws + 0);                       // 64 MB
    __hip_bfloat16* t1 = (__hip_bfloat16*)(ws + 67108864);       // 64 MB
    __hip_bfloat16* t2 = (__hip_bfloat16*)(ws + 134217728);      // 128 MB
    float*          x1 = (float*)(ws + 268435456);               // 1 MB
    float*          x2 = (float*)(ws + 269484032);               // 4 MB
    float*          x3 = (float*)(ws + 273678336);               // 16 MB
    // bf16 weight buffers reuse x3's region — x3 is dead after gemm4 (stream-ordered)
    char* wb = ws + 273678336;
    __hip_bfloat16* Wh1 = (__hip_bfloat16*)(wb);                 // 48 KB
    __hip_bfloat16* Wl1 = (__hip_bfloat16*)(wb + 65536);
    __hip_bfloat16* Wh2 = (__hip_bfloat16*)(wb + 131072);        // 192 KB
    __hip_bfloat16* Wl2 = (__hip_bfloat16*)(wb + 327680);
    __hip_bfloat16* Wh3 = (__hip_bfloat16*)(wb + 524288);        // 768 KB
    __hip_bfloat16* Wl3 = (__hip_bfloat16*)(wb + 1310720);

    dim3 blk(256);

    // MLP stack (fp32 VALU — next optimization target)
    gemm_leaky_kernel<<<dim3(1, 64),  blk, 0, stream>>>(trees, W1, b1, x1, B, 64, 16);
    gemm_leaky_kernel<<<dim3(4, 64),  blk, 0, stream>>>(x1, W2, b2, x2, B, 256, 64);
    gemm_leaky_kernel<<<dim3(16, 64), blk, 0, stream>>>(x2, W3, b3, x3, B, 1024, 256);
    gemm_leaky_kernel<<<dim3(64, 64), blk, 0, stream>>>(x3, W4, b4, x4, B, 4096, 1024);

    // conv weights -> bf16 hi/lo (runs after gemm4 has consumed x3)
    wcast_kernel<<<96,   blk, 0, stream>>>(cw1, Wh1, Wl1, 128 * 192);
    wcast_kernel<<<384,  blk, 0, stream>>>(cw2, Wh2, Wl2, 256 * 384);
    wcast_kernel<<<1536, blk, 0, stream>>>(cw3, Wh3, Wl3, 512 * 768);

    // fused conv + LN + leaky, one block per sample
    conv_ln_kernel<64, 128, float, __hip_bfloat16>
        <<<4096, blk, 0, stream>>>(x4, indexes, Wh1, Wl1, cb1, t1);
    conv_ln_kernel<128, 256, __hip_bfloat16, __hip_bfloat16>
        <<<4096, blk, 0, stream>>>(t1, indexes, Wh2, Wl2, cb2, t2);
    conv_ln_kernel<256, 512, __hip_bfloat16, float>
        <<<4096, blk, 0, stream>>>(t2, indexes, Wh3, Wl3, cb3, out);
}

// Round 3
// 2602.349 us; speedup vs baseline: 2.0275x; 1.0749x over previous
//
#include <hip/hip_runtime.h>
#include <hip/hip_bf16.h>

// TreeDecoder: B=4096, MLP 16->64->256->1024->4096 (leaky), reshape (B,64,64),
// then 3x [BinaryTreeConv -> TreeLayerNorm -> LeakyReLU], out (B,512,64) fp32.
//
// v2 of the MFMA conv: per-sample input staged to LDS once; MFMA B-fragments
// gathered per-wave directly from LDS (ds_read_u16 + pack) with ZERO barriers
// in the K-loop. Weights hi/lo bf16 split (no weight quantization error).

typedef short s16x8 __attribute__((ext_vector_type(8)));
typedef float f32x4 __attribute__((ext_vector_type(4)));
typedef unsigned int u32x4 __attribute__((ext_vector_type(4)));
typedef unsigned int u32x2 __attribute__((ext_vector_type(2)));

__device__ __forceinline__ float leaky(float v) { return v > 0.0f ? v : 0.01f * v; }

__device__ __forceinline__ unsigned short bf_bits(float f) {
    __hip_bfloat16 h = __float2bfloat16(f);
    return __builtin_bit_cast(unsigned short, h);
}
__device__ __forceinline__ void cvt_store(float* p, float v) { *p = v; }
__device__ __forceinline__ void cvt_store(__hip_bfloat16* p, float v) { *p = __float2bfloat16(v); }

// ---------------- MLP GEMM (unchanged from verified baseline) ----------------
__global__ __launch_bounds__(256) void gemm_leaky_kernel(
    const float* __restrict__ A, const float* __restrict__ W,
    const float* __restrict__ bias, float* __restrict__ Cmat,
    int M, int N, int K)
{
    __shared__ float As[16][68];
    __shared__ float Ws[16][68];
    const int tid = threadIdx.x;
    const int tx = tid & 15, ty = tid >> 4;
    const int n0 = blockIdx.x * 64, m0 = blockIdx.y * 64;
    const int row = tid >> 2, kq = tid & 3;
    float acc[4][4] = {};

    for (int k0 = 0; k0 < K; k0 += 16) {
        const float4 a = *(const float4*)&A[(size_t)(m0 + row) * K + k0 + kq * 4];
        const float4 w = *(const float4*)&W[(size_t)(n0 + row) * K + k0 + kq * 4];
        __syncthreads();
        As[kq*4+0][row] = a.x; As[kq*4+1][row] = a.y; As[kq*4+2][row] = a.z; As[kq*4+3][row] = a.w;
        Ws[kq*4+0][row] = w.x; Ws[kq*4+1][row] = w.y; Ws[kq*4+2][row] = w.z; Ws[kq*4+3][row] = w.w;
        __syncthreads();
        #pragma unroll
        for (int kk = 0; kk < 16; ++kk) {
            float avv[4], wvv[4];
            *(float4*)avv = *(const float4*)&As[kk][ty * 4];
            *(float4*)wvv = *(const float4*)&Ws[kk][tx * 4];
            #pragma unroll
            for (int i = 0; i < 4; ++i)
                #pragma unroll
                for (int j = 0; j < 4; ++j)
                    acc[i][j] = fmaf(avv[i], wvv[j], acc[i][j]);
        }
    }
    #pragma unroll
    for (int i = 0; i < 4; ++i) {
        const int m = m0 + ty * 4 + i;
        float4 r;
        r.x = leaky(acc[i][0] + bias[n0 + tx*4 + 0]);
        r.y = leaky(acc[i][1] + bias[n0 + tx*4 + 1]);
        r.z = leaky(acc[i][2] + bias[n0 + tx*4 + 2]);
        r.w = leaky(acc[i][3] + bias[n0 + tx*4 + 3]);
        *(float4*)&Cmat[(size_t)m * N + n0 + tx * 4] = r;
    }
}

// ---------------- weight fp32 -> bf16 hi/lo split ----------------
__global__ __launch_bounds__(256) void wcast_kernel(
    const float* __restrict__ in, __hip_bfloat16* __restrict__ hi,
    __hip_bfloat16* __restrict__ lo, int n)
{
    const int i = blockIdx.x * 256 + threadIdx.x;
    if (i < n) {
        const float w = in[i];
        const __hip_bfloat16 h = __float2bfloat16(w);
        hi[i] = h;
        lo[i] = __float2bfloat16(w - __bfloat162float(h));
    }
}

// ---------------- fused BinaryTreeConv + TreeLayerNorm + LeakyReLU (v2) ----------------
// One block (256 thr = 4 waves) per sample. Input staged to LDS (bf16 [C][64]) once;
// each wave gathers its MFMA B-fragments straight from LDS -> no barriers in K-loop.
// Wave w computes o-rows [w*O/4,(w+1)*O/4); epilogue: block LN reduce + stores.
template <int C, int O, typename Tin, typename Tout>
__global__ __launch_bounds__(256, 2) void conv_ln_kernel(
    const Tin* __restrict__ x, const int* __restrict__ idx,
    const __hip_bfloat16* __restrict__ Whi, const __hip_bfloat16* __restrict__ Wlo,
    const float* __restrict__ bias, Tout* __restrict__ outp)
{
    constexpr int K = 3 * C;
    constexpr int KSTEPS = K / 32;
    constexpr int OT = O / 64;              // 16-row o-tiles per wave
    __shared__ __align__(16) unsigned short xl[C * 64];   // staged input, bf16 [C][64]
    __shared__ int   idxl[192];
    __shared__ float red[12];

    const int tid  = (int)threadIdx.x;
    const int b    = (int)blockIdx.x;
    const int lane = tid & 63;
    const int wv   = tid >> 6;
    const int col  = lane & 15;             // B free dim (node col) / A row (o)
    const int kg   = lane >> 4;             // k-group: element e covers k = kg*8+e

    // ---- stage input to LDS (coalesced), bf16 ----
    if constexpr (sizeof(Tin) == 4) {       // fp32 input (conv1): convert on stage
        const float4* src = (const float4*)(x + (size_t)b * C * 64);
        #pragma unroll
        for (int it = 0; it < (C * 64) / (4 * 256); ++it) {
            const float4 v = src[it * 256 + tid];
            u32x2 p;
            p.x = (unsigned int)bf_bits(v.x) | ((unsigned int)bf_bits(v.y) << 16);
            p.y = (unsigned int)bf_bits(v.z) | ((unsigned int)bf_bits(v.w) << 16);
            *(u32x2*)&xl[(it * 256 + tid) * 4] = p;
        }
    } else {                                // bf16 input: verbatim copy
        const u32x4* src = (const u32x4*)(x + (size_t)b * C * 64);
        #pragma unroll
        for (int it = 0; it < (C * 128) / (16 * 256); ++it)
            *(u32x4*)&xl[(it * 256 + tid) * 8] = src[it * 256 + tid];
    }
    if (tid < 189) idxl[tid] = idx[b * 189 + tid];
    __syncthreads();

    // ---- per-lane node index triples (node = nt*16+col; node 63 = dummy, discarded) ----
    int j0[4], j1[4], j2[4];
    #pragma unroll
    for (int nt = 0; nt < 4; ++nt) {
        const int node = nt * 16 + col;
        if (node < 63) {
            j0[nt] = idxl[node * 3 + 0];
            j1[nt] = idxl[node * 3 + 1];
            j2[nt] = idxl[node * 3 + 2];
        } else {
            j0[nt] = 0; j1[nt] = 0; j2[nt] = 0;
        }
    }

    const int ob = wv * (O / 4);
    const __hip_bfloat16* wh = Whi + (size_t)(ob + col) * K + kg * 8;
    const __hip_bfloat16* wl = Wlo + (size_t)(ob + col) * K + kg * 8;

    f32x4 acc[OT][4];
    #pragma unroll
    for (int t = 0; t < OT; ++t)
        #pragma unroll
        for (int nt = 0; nt < 4; ++nt) acc[t][nt] = (f32x4)(0.0f);

    // ---- K-loop: no barriers; gather B-frags from LDS, A-frags from L2 ----
    for (int s = 0; s < KSTEPS; ++s) {
        const int k0 = s * 32 + kg * 8;
        int cc = k0 / 3;
        int rr = k0 - cc * 3;
        unsigned int wd[4][4] = {};         // [nt][u32 pair] -- static indices only
        #pragma unroll
        for (int j = 0; j < 8; ++j) {
            const unsigned short* xr = &xl[cc * 64];
            #pragma unroll
            for (int nt = 0; nt < 4; ++nt) {
                const int jv = (rr == 0) ? j0[nt] : ((rr == 1) ? j1[nt] : j2[nt]);
                wd[nt][j >> 1] |= ((unsigned int)xr[jv]) << ((j & 1) * 16);
            }
            ++rr;
            const int adv = (rr == 3) ? 1 : 0;
            cc += adv;
            rr = adv ? 0 : rr;
        }
        s16x8 bfr[4];
        #pragma unroll
        for (int nt = 0; nt < 4; ++nt) {
            u32x4 t4 = {wd[nt][0], wd[nt][1], wd[nt][2], wd[nt][3]};
            bfr[nt] = __builtin_bit_cast(s16x8, t4);
        }
        #pragma unroll
        for (int t = 0; t < OT; ++t) {
            const s16x8 ah = *(const s16x8*)(const void*)(wh + (size_t)t * 16 * K + s * 32);
            const s16x8 al = *(const s16x8*)(const void*)(wl + (size_t)t * 16 * K + s * 32);
            #pragma unroll
            for (int nt = 0; nt < 4; ++nt)
                acc[t][nt] = __builtin_amdgcn_mfma_f32_16x16x32_bf16(ah, bfr[nt], acc[t][nt], 0, 0, 0);
            #pragma unroll
            for (int nt = 0; nt < 4; ++nt)
                acc[t][nt] = __builtin_amdgcn_mfma_f32_16x16x32_bf16(al, bfr[nt], acc[t][nt], 0, 0, 0);
        }
    }

    // ---- bias + per-sample stats (zero slots contribute 0; count = O*64 incl. them) ----
    float s1 = 0.0f, s2 = 0.0f;
    #pragma unroll
    for (int t = 0; t < OT; ++t) {
        #pragma unroll
        for (int r = 0; r < 4; ++r) {
            const float bo = bias[ob + t * 16 + kg * 4 + r];
            #pragma unroll
            for (int nt = 0; nt < 4; ++nt) {
                const float v = acc[t][nt][r] + bo;
                acc[t][nt][r] = v;
                if (nt < 3 || col < 15) { s1 += v; s2 += v * v; }   // node = nt*16+col < 63
            }
        }
    }
    #pragma unroll
    for (int off = 32; off > 0; off >>= 1) {
        s1 += __shfl_down(s1, off, 64);
        s2 += __shfl_down(s2, off, 64);
    }
    if (lane == 0) { red[wv * 2] = s1; red[wv * 2 + 1] = s2; }
    __syncthreads();
    if (tid == 0) {
        const float a1 = red[0] + red[2] + red[4] + red[6];
        const float a2 = red[1] + red[3] + red[5] + red[7];
        const float cnt = (float)(O * 64);
        const float mean = a1 / cnt;
        float var = (a2 - a1 * mean) / (cnt - 1.0f);   // torch unbiased std
        var = fmaxf(var, 0.0f);
        red[8] = mean;
        red[9] = 1.0f / (sqrtf(var) + 1e-5f);
    }
    __syncthreads();
    const float mean = red[8], inv = red[9];

    Tout* op = outp + (size_t)b * O * 64;
    #pragma unroll
    for (int t = 0; t < OT; ++t) {
        #pragma unroll
        for (int r = 0; r < 4; ++r) {
            const int o = ob + t * 16 + kg * 4 + r;
            #pragma unroll
            for (int nt = 0; nt < 4; ++nt) {
                const int node = nt * 16 + col;
                if (node < 63)
                    cvt_store(&op[(size_t)o * 64 + node + 1], leaky((acc[t][nt][r] - mean) * inv));
            }
        }
    }
    const float z0 = leaky((0.0f - mean) * inv);        // LN of the zero pad slot
    for (int o = tid; o < O; o += 256) cvt_store(&op[(size_t)o * 64], z0);
}

extern "C" void kernel_launch(void* const* d_in, const int* in_sizes, int n_in,
                              void* d_out, int out_size, void* d_ws, size_t ws_size,
                              hipStream_t stream)
{
    const int B = 4096;
    const float* trees = (const float*)d_in[0];
    const int*   indexes = (const int*)d_in[1];
    const float* W1 = (const float*)d_in[2];
    const float* b1 = (const float*)d_in[3];
    const float* W2 = (const float*)d_in[4];
    const float* b2 = (const float*)d_in[5];
    const float* W3 = (const float*)d_in[6];
    const float* b3 = (const float*)d_in[7];
    const float* W4 = (const float*)d_in[8];
    const float* b4 = (const float*)d_in[9];
    const float* cw1 = (const float*)d_in[10];
    const float* cb1 = (const float*)d_in[11];
    const float* cw2 = (const float*)d_in[12];
    const float* cb2 = (const float*)d_in[13];
    const float* cw3 = (const float*)d_in[14];
    const float* cb3 = (const float*)d_in[15];
    float* out = (float*)d_out;
    char* ws = (char*)d_ws;

    // workspace layout (bytes) — same footprint as baseline (~277 MB)
    float*          x4 = (float*)(ws + 0);                       // 64 MB
    __hip_bfloat16* t1 = (__hip_bfloat16*)(ws + 67108864);       // 64 MB
    __hip_bfloat16* t2 = (__hip_bfloat16*)(ws + 134217728);      // 128 MB
    float*          x1 = (float*)(ws + 268435456);               // 1 MB
    float*          x2 = (float*)(ws + 269484032);               // 4 MB
    float*          x3 = (float*)(ws + 273678336);               // 16 MB
    // bf16 weight buffers reuse x3's region — x3 is dead after gemm4 (stream-ordered)
    char* wb = ws + 273678336;
    __hip_bfloat16* Wh1 = (__hip_bfloat16*)(wb);                 // 48 KB
    __hip_bfloat16* Wl1 = (__hip_bfloat16*)(wb + 65536);
    __hip_bfloat16* Wh2 = (__hip_bfloat16*)(wb + 131072);        // 192 KB
    __hip_bfloat16* Wl2 = (__hip_bfloat16*)(wb + 327680);
    __hip_bfloat16* Wh3 = (__hip_bfloat16*)(wb + 524288);        // 768 KB
    __hip_bfloat16* Wl3 = (__hip_bfloat16*)(wb + 1310720);

    dim3 blk(256);

    // MLP stack (fp32 VALU — next optimization target)
    gemm_leaky_kernel<<<dim3(1, 64),  blk, 0, stream>>>(trees, W1, b1, x1, B, 64, 16);
    gemm_leaky_kernel<<<dim3(4, 64),  blk, 0, stream>>>(x1, W2, b2, x2, B, 256, 64);
    gemm_leaky_kernel<<<dim3(16, 64), blk, 0, stream>>>(x2, W3, b3, x3, B, 1024, 256);
    gemm_leaky_kernel<<<dim3(64, 64), blk, 0, stream>>>(x3, W4, b4, x4, B, 4096, 1024);

    // conv weights -> bf16 hi/lo (runs after gemm4 has consumed x3)
    wcast_kernel<<<96,   blk, 0, stream>>>(cw1, Wh1, Wl1, 128 * 192);
    wcast_kernel<<<384,  blk, 0, stream>>>(cw2, Wh2, Wl2, 256 * 384);
    wcast_kernel<<<1536, blk, 0, stream>>>(cw3, Wh3, Wl3, 512 * 768);

    // fused conv + LN + leaky, one block per sample
    conv_ln_kernel<64, 128, float, __hip_bfloat16>
        <<<4096, blk, 0, stream>>>(x4, indexes, Wh1, Wl1, cb1, t1);
    conv_ln_kernel<128, 256, __hip_bfloat16, __hip_bfloat16>
        <<<4096, blk, 0, stream>>>(t1, indexes, Wh2, Wl2, cb2, t2);
    conv_ln_kernel<256, 512, __hip_bfloat16, float>
        <<<4096, blk, 0, stream>>>(t2, indexes, Wh3, Wl3, cb3, out);
}

// Round 4
// 2058.009 us; speedup vs baseline: 2.5637x; 1.2645x over previous
//
#include <hip/hip_runtime.h>
#include <hip/hip_bf16.h>

// TreeDecoder: B=4096, MLP 16->64->256->1024->4096 (leaky), reshape (B,64,64),
// then 3x [BinaryTreeConv -> TreeLayerNorm -> LeakyReLU], out (B,512,64) fp32.
//
// v3 conv: 512-thread blocks (8 waves), chunked SHARED gather: per 192-k chunk
// all threads cooperatively build G[node][k] (bf16) in LDS once (24 ds_read_u16
// + 3 ds_write_b128 per thread), then MFMA reads B-frags as aligned ds_read_b128.
// Accumulator 64 regs/wave -> launch_bounds(512,4) targets 16 waves/CU.

typedef short s16x8 __attribute__((ext_vector_type(8)));
typedef float f32x4 __attribute__((ext_vector_type(4)));
typedef unsigned int u32x4 __attribute__((ext_vector_type(4)));
typedef unsigned int u32x2 __attribute__((ext_vector_type(2)));

__device__ __forceinline__ float leaky(float v) { return v > 0.0f ? v : 0.01f * v; }

__device__ __forceinline__ unsigned short bf_bits(float f) {
    __hip_bfloat16 h = __float2bfloat16(f);
    return __builtin_bit_cast(unsigned short, h);
}
__device__ __forceinline__ void cvt_store(float* p, float v) { *p = v; }
__device__ __forceinline__ void cvt_store(__hip_bfloat16* p, float v) { *p = __float2bfloat16(v); }

// ---------------- MLP GEMM (unchanged from verified baseline) ----------------
__global__ __launch_bounds__(256) void gemm_leaky_kernel(
    const float* __restrict__ A, const float* __restrict__ W,
    const float* __restrict__ bias, float* __restrict__ Cmat,
    int M, int N, int K)
{
    __shared__ float As[16][68];
    __shared__ float Ws[16][68];
    const int tid = threadIdx.x;
    const int tx = tid & 15, ty = tid >> 4;
    const int n0 = blockIdx.x * 64, m0 = blockIdx.y * 64;
    const int row = tid >> 2, kq = tid & 3;
    float acc[4][4] = {};

    for (int k0 = 0; k0 < K; k0 += 16) {
        const float4 a = *(const float4*)&A[(size_t)(m0 + row) * K + k0 + kq * 4];
        const float4 w = *(const float4*)&W[(size_t)(n0 + row) * K + k0 + kq * 4];
        __syncthreads();
        As[kq*4+0][row] = a.x; As[kq*4+1][row] = a.y; As[kq*4+2][row] = a.z; As[kq*4+3][row] = a.w;
        Ws[kq*4+0][row] = w.x; Ws[kq*4+1][row] = w.y; Ws[kq*4+2][row] = w.z; Ws[kq*4+3][row] = w.w;
        __syncthreads();
        #pragma unroll
        for (int kk = 0; kk < 16; ++kk) {
            float avv[4], wvv[4];
            *(float4*)avv = *(const float4*)&As[kk][ty * 4];
            *(float4*)wvv = *(const float4*)&Ws[kk][tx * 4];
            #pragma unroll
            for (int i = 0; i < 4; ++i)
                #pragma unroll
                for (int j = 0; j < 4; ++j)
                    acc[i][j] = fmaf(avv[i], wvv[j], acc[i][j]);
        }
    }
    #pragma unroll
    for (int i = 0; i < 4; ++i) {
        const int m = m0 + ty * 4 + i;
        float4 r;
        r.x = leaky(acc[i][0] + bias[n0 + tx*4 + 0]);
        r.y = leaky(acc[i][1] + bias[n0 + tx*4 + 1]);
        r.z = leaky(acc[i][2] + bias[n0 + tx*4 + 2]);
        r.w = leaky(acc[i][3] + bias[n0 + tx*4 + 3]);
        *(float4*)&Cmat[(size_t)m * N + n0 + tx * 4] = r;
    }
}

// ---------------- weight fp32 -> bf16 hi/lo split ----------------
__global__ __launch_bounds__(256) void wcast_kernel(
    const float* __restrict__ in, __hip_bfloat16* __restrict__ hi,
    __hip_bfloat16* __restrict__ lo, int n)
{
    const int i = blockIdx.x * 256 + threadIdx.x;
    if (i < n) {
        const float w = in[i];
        const __hip_bfloat16 h = __float2bfloat16(w);
        hi[i] = h;
        lo[i] = __float2bfloat16(w - __bfloat162float(h));
    }
}

// ---------------- fused BinaryTreeConv + TreeLayerNorm + LeakyReLU (v3) ----------------
// One block (512 thr = 8 waves) per sample. Wave w owns o-rows [w*O/8,(w+1)*O/8).
// K processed in 192-k chunks: cooperative gather into G[64 node][264 u16 pitch],
// then 6 MFMA steps reading aligned b128 B-frags. 2 barriers per chunk.
template <int C, int O, typename Tin, typename Tout>
__global__ __launch_bounds__(512, 4) void conv_ln_kernel(
    const Tin* __restrict__ x, const int* __restrict__ idx,
    const __hip_bfloat16* __restrict__ Whi, const __hip_bfloat16* __restrict__ Wlo,
    const float* __restrict__ bias, Tout* __restrict__ outp)
{
    constexpr int K = 3 * C;
    constexpr int NCHUNK = K / 192;
    constexpr int OT = O / 128;             // 16-row o-tiles per wave
    constexpr int GP = 264;                 // G row pitch in u16 (528 B, 16B-multiple)
    __shared__ __align__(16) unsigned short xl[C * 64];   // staged input bf16 [C][64]
    __shared__ __align__(16) unsigned short G[64 * GP];   // gathered chunk [node][192k]
    __shared__ int   idxl[192];
    __shared__ float red[18];

    const int tid  = (int)threadIdx.x;
    const int b    = (int)blockIdx.x;
    const int lane = tid & 63;
    const int wv   = tid >> 6;
    const int col  = lane & 15;             // B node-col / A o-row within tile
    const int kg   = lane >> 4;             // k-group: element e covers k = kg*8+e

    // ---- stage input to LDS (coalesced), bf16 ----
    if constexpr (sizeof(Tin) == 4) {       // fp32 input (conv1): convert on stage
        const float4* src = (const float4*)(x + (size_t)b * C * 64);
        #pragma unroll
        for (int it = 0; it < (C * 64) / (4 * 512); ++it) {
            const float4 v = src[it * 512 + tid];
            u32x2 p;
            p.x = (unsigned int)bf_bits(v.x) | ((unsigned int)bf_bits(v.y) << 16);
            p.y = (unsigned int)bf_bits(v.z) | ((unsigned int)bf_bits(v.w) << 16);
            *(u32x2*)&xl[(it * 512 + tid) * 4] = p;
        }
    } else {                                // bf16 input: verbatim copy
        const u32x4* src = (const u32x4*)(x + (size_t)b * C * 64);
        #pragma unroll
        for (int it = 0; it < (C * 64) / (8 * 512); ++it)
            *(u32x4*)&xl[(it * 512 + tid) * 8] = src[it * 512 + tid];
    }
    if (tid < 192) idxl[tid] = (tid < 189) ? idx[b * 189 + tid] : 0;
    __syncthreads();

    // gather role: thread = (gnode, gi); fills G[gnode][gi*24 .. gi*24+24)
    const int gnode = tid >> 3;
    const int gi    = tid & 7;
    const int gj0 = idxl[gnode * 3 + 0];
    const int gj1 = idxl[gnode * 3 + 1];
    const int gj2 = idxl[gnode * 3 + 2];
    unsigned short* grow = &G[gnode * GP + gi * 24];

    const int ob = wv * (O / 8);
    const __hip_bfloat16* wh = Whi + (size_t)(ob + col) * K + kg * 8;
    const __hip_bfloat16* wl = Wlo + (size_t)(ob + col) * K + kg * 8;

    f32x4 acc[OT][4];
    #pragma unroll
    for (int t = 0; t < OT; ++t)
        #pragma unroll
        for (int nt = 0; nt < 4; ++nt) acc[t][nt] = (f32x4)(0.0f);

    #pragma unroll 1
    for (int ch = 0; ch < NCHUNK; ++ch) {
        // ---- cooperative gather of chunk ch into G ----
        {
            const int c_base = ch * 64 + gi * 8;
            unsigned int w[12];
            #pragma unroll
            for (int t3 = 0; t3 < 8; ++t3) {
                const unsigned short* xr = &xl[(c_base + t3) << 6];
                const unsigned int v0 = xr[gj0];
                const unsigned int v1 = xr[gj1];
                const unsigned int v2 = xr[gj2];
                const int kkb = t3 * 3;     // 0,3,...,21 (compile-time)
                // kk = kkb+0 (even/odd alternates; kk strictly increasing 0..23)
                if ((kkb & 1) == 0) w[kkb >> 1] = v0; else w[kkb >> 1] |= v0 << 16;
                if (((kkb + 1) & 1) == 0) w[(kkb + 1) >> 1] = v1; else w[(kkb + 1) >> 1] |= v1 << 16;
                if (((kkb + 2) & 1) == 0) w[(kkb + 2) >> 1] = v2; else w[(kkb + 2) >> 1] |= v2 << 16;
            }
            u32x4 q0 = {w[0], w[1], w[2], w[3]};
            u32x4 q1 = {w[4], w[5], w[6], w[7]};
            u32x4 q2 = {w[8], w[9], w[10], w[11]};
            *(u32x4*)(grow + 0)  = q0;
            *(u32x4*)(grow + 8)  = q1;
            *(u32x4*)(grow + 16) = q2;
        }
        __syncthreads();                    // G ready

        // ---- MFMA over 6 k-steps of this chunk ----
        #pragma unroll 1
        for (int s = 0; s < 6; ++s) {
            s16x8 bfr[4];
            #pragma unroll
            for (int nt = 0; nt < 4; ++nt)
                bfr[nt] = *(const s16x8*)(const void*)&G[(nt * 16 + col) * GP + s * 32 + kg * 8];
            const size_t kofs = (size_t)(ch * 192 + s * 32);
            #pragma unroll
            for (int t = 0; t < OT; ++t) {
                const s16x8 ah = *(const s16x8*)(const void*)(wh + (size_t)t * 16 * K + kofs);
                const s16x8 al = *(const s16x8*)(const void*)(wl + (size_t)t * 16 * K + kofs);
                #pragma unroll
                for (int nt = 0; nt < 4; ++nt)
                    acc[t][nt] = __builtin_amdgcn_mfma_f32_16x16x32_bf16(ah, bfr[nt], acc[t][nt], 0, 0, 0);
                #pragma unroll
                for (int nt = 0; nt < 4; ++nt)
                    acc[t][nt] = __builtin_amdgcn_mfma_f32_16x16x32_bf16(al, bfr[nt], acc[t][nt], 0, 0, 0);
            }
        }
        __syncthreads();                    // before next chunk overwrites G
    }

    // ---- bias + per-sample stats (zero slots contribute 0; count = O*64 incl. them) ----
    float s1 = 0.0f, s2 = 0.0f;
    #pragma unroll
    for (int t = 0; t < OT; ++t) {
        #pragma unroll
        for (int r = 0; r < 4; ++r) {
            const float bo = bias[ob + t * 16 + kg * 4 + r];
            #pragma unroll
            for (int nt = 0; nt < 4; ++nt) {
                const float v = acc[t][nt][r] + bo;
                acc[t][nt][r] = v;
                if (nt < 3 || col < 15) { s1 += v; s2 += v * v; }   // node = nt*16+col < 63
            }
        }
    }
    #pragma unroll
    for (int off = 32; off > 0; off >>= 1) {
        s1 += __shfl_down(s1, off, 64);
        s2 += __shfl_down(s2, off, 64);
    }
    if (lane == 0) { red[wv * 2] = s1; red[wv * 2 + 1] = s2; }
    __syncthreads();
    if (tid == 0) {
        float a1 = 0.0f, a2 = 0.0f;
        #pragma unroll
        for (int wq = 0; wq < 8; ++wq) { a1 += red[wq * 2]; a2 += red[wq * 2 + 1]; }
        const float cnt = (float)(O * 64);
        const float mean = a1 / cnt;
        float var = (a2 - a1 * mean) / (cnt - 1.0f);   // torch unbiased std
        var = fmaxf(var, 0.0f);
        red[16] = mean;
        red[17] = 1.0f / (sqrtf(var) + 1e-5f);
    }
    __syncthreads();
    const float mean = red[16], inv = red[17];

    Tout* op = outp + (size_t)b * O * 64;
    #pragma unroll
    for (int t = 0; t < OT; ++t) {
        #pragma unroll
        for (int r = 0; r < 4; ++r) {
            const int o = ob + t * 16 + kg * 4 + r;
            #pragma unroll
            for (int nt = 0; nt < 4; ++nt) {
                const int node = nt * 16 + col;
                if (node < 63)
                    cvt_store(&op[(size_t)o * 64 + node + 1], leaky((acc[t][nt][r] - mean) * inv));
            }
        }
    }
    const float z0 = leaky((0.0f - mean) * inv);        // LN of the zero pad slot
    for (int o = tid; o < O; o += 512) cvt_store(&op[(size_t)o * 64], z0);
}

extern "C" void kernel_launch(void* const* d_in, const int* in_sizes, int n_in,
                              void* d_out, int out_size, void* d_ws, size_t ws_size,
                              hipStream_t stream)
{
    const int B = 4096;
    const float* trees = (const float*)d_in[0];
    const int*   indexes = (const int*)d_in[1];
    const float* W1 = (const float*)d_in[2];
    const float* b1 = (const float*)d_in[3];
    const float* W2 = (const float*)d_in[4];
    const float* b2 = (const float*)d_in[5];
    const float* W3 = (const float*)d_in[6];
    const float* b3 = (const float*)d_in[7];
    const float* W4 = (const float*)d_in[8];
    const float* b4 = (const float*)d_in[9];
    const float* cw1 = (const float*)d_in[10];
    const float* cb1 = (const float*)d_in[11];
    const float* cw2 = (const float*)d_in[12];
    const float* cb2 = (const float*)d_in[13];
    const float* cw3 = (const float*)d_in[14];
    const float* cb3 = (const float*)d_in[15];
    float* out = (float*)d_out;
    char* ws = (char*)d_ws;

    // workspace layout (bytes) — same footprint as baseline (~277 MB)
    float*          x4 = (float*)(ws + 0);                       // 64 MB
    __hip_bfloat16* t1 = (__hip_bfloat16*)(ws + 67108864);       // 64 MB
    __hip_bfloat16* t2 = (__hip_bfloat16*)(ws + 134217728);      // 128 MB
    float*          x1 = (float*)(ws + 268435456);               // 1 MB
    float*          x2 = (float*)(ws + 269484032);               // 4 MB
    float*          x3 = (float*)(ws + 273678336);               // 16 MB
    // bf16 weight buffers reuse x3's region — x3 is dead after gemm4 (stream-ordered)
    char* wb = ws + 273678336;
    __hip_bfloat16* Wh1 = (__hip_bfloat16*)(wb);                 // 48 KB
    __hip_bfloat16* Wl1 = (__hip_bfloat16*)(wb + 65536);
    __hip_bfloat16* Wh2 = (__hip_bfloat16*)(wb + 131072);        // 192 KB
    __hip_bfloat16* Wl2 = (__hip_bfloat16*)(wb + 327680);
    __hip_bfloat16* Wh3 = (__hip_bfloat16*)(wb + 524288);        // 768 KB
    __hip_bfloat16* Wl3 = (__hip_bfloat16*)(wb + 1310720);

    dim3 blk(256);
    dim3 blk512(512);

    // MLP stack (fp32 VALU — next optimization target)
    gemm_leaky_kernel<<<dim3(1, 64),  blk, 0, stream>>>(trees, W1, b1, x1, B, 64, 16);
    gemm_leaky_kernel<<<dim3(4, 64),  blk, 0, stream>>>(x1, W2, b2, x2, B, 256, 64);
    gemm_leaky_kernel<<<dim3(16, 64), blk, 0, stream>>>(x2, W3, b3, x3, B, 1024, 256);
    gemm_leaky_kernel<<<dim3(64, 64), blk, 0, stream>>>(x3, W4, b4, x4, B, 4096, 1024);

    // conv weights -> bf16 hi/lo (runs after gemm4 has consumed x3)
    wcast_kernel<<<96,   blk, 0, stream>>>(cw1, Wh1, Wl1, 128 * 192);
    wcast_kernel<<<384,  blk, 0, stream>>>(cw2, Wh2, Wl2, 256 * 384);
    wcast_kernel<<<1536, blk, 0, stream>>>(cw3, Wh3, Wl3, 512 * 768);

    // fused conv + LN + leaky, one block per sample
    conv_ln_kernel<64, 128, float, __hip_bfloat16>
        <<<4096, blk512, 0, stream>>>(x4, indexes, Wh1, Wl1, cb1, t1);
    conv_ln_kernel<128, 256, __hip_bfloat16, __hip_bfloat16>
        <<<4096, blk512, 0, stream>>>(t1, indexes, Wh2, Wl2, cb2, t2);
    conv_ln_kernel<256, 512, __hip_bfloat16, float>
        <<<4096, blk512, 0, stream>>>(t2, indexes, Wh3, Wl3, cb3, out);
}